// Round 6
// baseline (12490.093 us; speedup 1.0000x reference)
//
#include <hip/hip_runtime.h>
#include <hip/hip_fp16.h>

#define Bsz 128
#define Tt  512
#define Ff  64
#define Hh  512

typedef _Float16 half8 __attribute__((ext_vector_type(8)));
typedef float f32x4 __attribute__((ext_vector_type(4)));
typedef unsigned long long ull;
typedef unsigned short u16;
typedef unsigned int uint;

#define KPAD 648   // Wlds row stride (halves): 324 dw, mod32=4 -> 2-way (free)
#define APAD 520   // Alds row stride (halves): 260 dw, mod32=4 -> 2-way (free)

union HU { _Float16 h; u16 u; };

__device__ __forceinline__ float sigf(float x)     { return 1.0f / (1.0f + __expf(-x)); }
__device__ __forceinline__ float tanhfast(float x) { return 1.0f - 2.0f / (__expf(2.0f * x) + 1.0f); }

// W_eff = Wd_hh + Wd_ih @ Wo  (decoder feedback folded; out becomes pure side-output)
__global__ __launch_bounds__(256) void prep_weff(
    const float* __restrict__ Wd_ih, const float* __restrict__ Wd_hh,
    const float* __restrict__ bd,    const float* __restrict__ Wo,
    const float* __restrict__ bo,    _Float16* __restrict__ W16,
    float* __restrict__ beff)
{
    int idx = blockIdx.x * 256 + threadIdx.x;   // [0, 2048*512)
    int g = idx >> 9, j = idx & 511;
    float acc = Wd_hh[idx];
    const float* wi = Wd_ih + g * Ff;
    #pragma unroll 8
    for (int f = 0; f < Ff; ++f) acc += wi[f] * Wo[f * Hh + j];
    W16[idx] = (_Float16)acc;
    if (j == 0) {
        float b = bd[g];
        for (int f = 0; f < Ff; ++f) b += wi[f] * bo[f];
        beff[g] = b;
    }
}

// Persistent LSTM, 8 groups x 32 members; NO barriers — pure tagged-word dataflow.
// State s (s=0 init, 1..512 enc, 513 latent, 514..1025 dec) lives in buffer s&1
// as 32-bit words {tag=s+1 (hi16) | fp16 h (lo16)}; consumers poll tags.
// Ping-pong is safe w/o flags: producing s+2 requires staging s+1 => all
// produced s+1 => all staged s (the buffer s+2 overwrites).
__global__ __launch_bounds__(256, 1) void lstm_persist(
    const float* __restrict__ ts,
    const float* __restrict__ We_ih, const float* __restrict__ We_hh,
    const float* __restrict__ be,
    const float* __restrict__ Wm,    const float* __restrict__ bm,
    const float* __restrict__ Wo,    const float* __restrict__ bo,
    const _Float16* __restrict__ Weff, const float* __restrict__ beff,
    uint* __restrict__ hbw,        // [2][8][16][512] tagged words (512 KB)
    float* __restrict__ out)
{
    __shared__ __align__(16) _Float16 Wlds[64 * KPAD];   // 82944 B (1 WG/CU)
    __shared__ __align__(16) _Float16 Alds[16 * APAD];   // 16640 B

    const int bid = blockIdx.x;
    const int g = bid & 7, m = bid >> 3;
    const int tid = threadIdx.x;
    const int w = tid >> 6, l = tid & 63;
    const int bL = l & 15, kg = l >> 4;
    const int jj = m * 16 + w * 4 + kg;
    const int gb0 = g * 16;

    uint* buf0 = hbw + (size_t)(0 * 8 + g) * 8192;
    uint* buf1 = hbw + (size_t)(1 * 8 + g) * 8192;

    // ---- stage state s -> Alds: poll 16 ull (32 tagged words) per thread ----
    auto stage = [&](int s) {
        const ull* p = (const ull*)((s & 1) ? buf1 : buf0) + tid * 16;
        const uint tg = (uint)(s + 1);
        ull u[16];
        int first = 1;
        for (;;) {
            if (!first) __builtin_amdgcn_s_sleep(1);
            first = 0;
            #pragma unroll
            for (int i = 0; i < 16; ++i)
                u[i] = __hip_atomic_load((ull*)(p + i), __ATOMIC_RELAXED,
                                         __HIP_MEMORY_SCOPE_AGENT);
            int ok = 1;
            #pragma unroll
            for (int i = 0; i < 16; ++i)
                ok &= (int)((((uint)(u[i] >> 16) & 0xffffu) == tg) &
                            (((uint)(u[i] >> 48)) == tg));
            if (ok) break;
        }
        const int b_ = tid >> 4, c0 = (tid & 15) * 32;
        #pragma unroll
        for (int i = 0; i < 8; ++i) {
            uint lo0 = (uint)u[2 * i] & 0xffffu;
            uint lo1 = ((uint)(u[2 * i] >> 32)) & 0xffffu;
            uint lo2 = (uint)u[2 * i + 1] & 0xffffu;
            uint lo3 = ((uint)(u[2 * i + 1] >> 32)) & 0xffffu;
            ull pk = (ull)(lo0 | (lo1 << 16)) | ((ull)(lo2 | (lo3 << 16)) << 32);
            *(ull*)&Alds[b_ * APAD + c0 + i * 4] = pk;
        }
    };

    // ---- publish state s: gather 4 cols per lane<16, tagged dword stores ----
    auto publish = [&](float hval, int s) {
        uint* dst = ((s & 1) ? buf1 : buf0) + (bL * 512 + m * 16 + w * 4);
        HU cv; cv.h = (_Float16)hval;
        int hv = (int)cv.u;
        int a0 = __shfl(hv, bL +  0, 64);
        int a1 = __shfl(hv, bL + 16, 64);
        int a2 = __shfl(hv, bL + 32, 64);
        int a3 = __shfl(hv, bL + 48, 64);
        if (l < 16) {
            uint tg = ((uint)(s + 1)) << 16;
            __hip_atomic_store(dst + 0, tg | ((uint)a0 & 0xffffu), __ATOMIC_RELAXED, __HIP_MEMORY_SCOPE_AGENT);
            __hip_atomic_store(dst + 1, tg | ((uint)a1 & 0xffffu), __ATOMIC_RELAXED, __HIP_MEMORY_SCOPE_AGENT);
            __hip_atomic_store(dst + 2, tg | ((uint)a2 & 0xffffu), __ATOMIC_RELAXED, __HIP_MEMORY_SCOPE_AGENT);
            __hip_atomic_store(dst + 3, tg | ((uint)a3 & 0xffffu), __ATOMIC_RELAXED, __HIP_MEMORY_SCOPE_AGENT);
        }
    };

    // ---- one-time: encoder weights -> LDS fp16 (rows R: jc=R>>2, gamma=R&3) ----
    for (int idx = tid; idx < 64 * 144; idx += 256) {
        int R = idx / 144, kq = idx - R * 144;
        int grow = (R & 3) * Hh + m * 16 + (R >> 2);
        float4 v;
        if (kq < 128) v = *(const float4*)(We_hh + (size_t)grow * Hh + kq * 4);
        else          v = *(const float4*)(We_ih + (size_t)grow * Ff + (kq - 128) * 4);
        _Float16* dst = &Wlds[R * KPAD + kq * 4];
        dst[0] = (_Float16)v.x; dst[1] = (_Float16)v.y;
        dst[2] = (_Float16)v.z; dst[3] = (_Float16)v.w;
    }
    // init state 0 (h=0, tag 1)
    if (l < 16) {
        uint* d0 = buf0 + (bL * 512 + m * 16 + w * 4);
        uint tg = 1u << 16;
        __hip_atomic_store(d0 + 0, tg, __ATOMIC_RELAXED, __HIP_MEMORY_SCOPE_AGENT);
        __hip_atomic_store(d0 + 1, tg, __ATOMIC_RELAXED, __HIP_MEMORY_SCOPE_AGENT);
        __hip_atomic_store(d0 + 2, tg, __ATOMIC_RELAXED, __HIP_MEMORY_SCOPE_AGENT);
        __hip_atomic_store(d0 + 3, tg, __ATOMIC_RELAXED, __HIP_MEMORY_SCOPE_AGENT);
    }
    float bias0 = be[0 * Hh + jj], bias1 = be[1 * Hh + jj],
          bias2 = be[2 * Hh + jj], bias3 = be[3 * Hh + jj];
    float c = 0.f;

    // =========================== encoder: 512 steps ===========================
    for (int t = 0; t < Tt; ++t) {
        const float* xp = ts + ((size_t)(gb0 + bL) * Tt + t) * Ff + kg * 8;
        float4 xa0 = *(const float4*)(xp);
        float4 xa1 = *(const float4*)(xp + 4);
        float4 xb0 = *(const float4*)(xp + 32);
        float4 xb1 = *(const float4*)(xp + 36);

        stage(t);              // h-state t
        __syncthreads();       // Alds (and, at t=0, Wlds) ready

        f32x4 acc0 = {0.f, 0.f, 0.f, 0.f}, acc1 = {0.f, 0.f, 0.f, 0.f};
        const _Float16* wrow = &Wlds[(w * 16 + bL) * KPAD + kg * 8];
        const _Float16* arow = &Alds[bL * APAD + kg * 8];
        #pragma unroll
        for (int kt = 0; kt < 16; ++kt) {
            half8 af = *(const half8*)(wrow + kt * 32);
            half8 bf = *(const half8*)(arow + kt * 32);
            if (kt & 1) acc1 = __builtin_amdgcn_mfma_f32_16x16x32_f16(af, bf, acc1, 0, 0, 0);
            else        acc0 = __builtin_amdgcn_mfma_f32_16x16x32_f16(af, bf, acc0, 0, 0, 0);
        }
        {   // x tail: kt=16 (cols 0..31), kt=17 (cols 32..63)
            half8 af = *(const half8*)(wrow + 16 * 32);
            half8 bf;
            bf[0]=(_Float16)xa0.x; bf[1]=(_Float16)xa0.y; bf[2]=(_Float16)xa0.z; bf[3]=(_Float16)xa0.w;
            bf[4]=(_Float16)xa1.x; bf[5]=(_Float16)xa1.y; bf[6]=(_Float16)xa1.z; bf[7]=(_Float16)xa1.w;
            acc0 = __builtin_amdgcn_mfma_f32_16x16x32_f16(af, bf, acc0, 0, 0, 0);
            half8 ag = *(const half8*)(wrow + 17 * 32);
            half8 bg;
            bg[0]=(_Float16)xb0.x; bg[1]=(_Float16)xb0.y; bg[2]=(_Float16)xb0.z; bg[3]=(_Float16)xb0.w;
            bg[4]=(_Float16)xb1.x; bg[5]=(_Float16)xb1.y; bg[6]=(_Float16)xb1.z; bg[7]=(_Float16)xb1.w;
            acc1 = __builtin_amdgcn_mfma_f32_16x16x32_f16(ag, bg, acc1, 0, 0, 0);
        }

        float gi = acc0[0] + acc1[0] + bias0;
        float gf = acc0[1] + acc1[1] + bias1;
        float gg = acc0[2] + acc1[2] + bias2;
        float go = acc0[3] + acc1[3] + bias3;
        c = sigf(gf) * c + sigf(gi) * tanhfast(gg);
        float h = sigf(go) * tanhfast(c);
        publish(h, t + 1);
        __syncthreads();       // all waves done reading Alds before next stage
    }

    // ====================== latent + decoder weight swap ======================
    {
        stage(512);            // h_enc
        __syncthreads();
        int b_ = tid & 15, jc2 = tid >> 4;      // == (bL, w*4+kg)
        int j2 = m * 16 + jc2;
        const float* wmr = Wm + (size_t)j2 * Hh;
        const _Float16* hr = &Alds[b_ * APAD];
        float acc = bm[j2];
        #pragma unroll 8
        for (int q = 0; q < 64; ++q) {
            half8 hv = *(const half8*)(hr + q * 8);
            float4 w0 = *(const float4*)(wmr + q * 8);
            float4 w1 = *(const float4*)(wmr + q * 8 + 4);
            acc += (float)hv[0]*w0.x + (float)hv[1]*w0.y + (float)hv[2]*w0.z + (float)hv[3]*w0.w
                 + (float)hv[4]*w1.x + (float)hv[5]*w1.y + (float)hv[6]*w1.z + (float)hv[7]*w1.w;
        }
        // overlay decoder weights (enc MFMA done: past t=511 trailing sync)
        for (int idx = tid; idx < 64 * 64; idx += 256) {
            int R = idx >> 6, q8 = idx & 63;
            int grow = (R & 3) * Hh + m * 16 + (R >> 2);
            *(half8*)&Wlds[R * KPAD + q8 * 8] =
                *(const half8*)(Weff + (size_t)grow * Hh + q8 * 8);
        }
        bias0 = beff[0 * Hh + jj]; bias1 = beff[1 * Hh + jj];
        bias2 = beff[2 * Hh + jj]; bias3 = beff[3 * Hh + jj];
        publish(acc, 513);     // h_lat becomes decoder h-state (c carries in regs)
        __syncthreads();       // Wlds overlay complete before decoder MFMAs
    }

    // =========================== decoder: 512 steps ===========================
    for (int k = 0; k < Tt; ++k) {
        stage(513 + k);
        __syncthreads();

        // out[:, 511-k, :] = h @ Wo.T + bo — remapped: octet lanes span 8 cols
        // (banks 4*(l&7), conflict-free), chunk = l>>3, reduce over chunks.
        {
            int c8 = l & 7, chunk = l >> 3;
            int pr = w * 8 + c8;
            int ob = pr & 15, fs = pr >> 4;
            int f = 2 * m + fs;
            const float* wor = Wo + (size_t)f * Hh + chunk * 64;
            const _Float16* ha = &Alds[ob * APAD + chunk * 64];
            float oa = 0.f;
            #pragma unroll
            for (int q = 0; q < 8; ++q) {
                half8 hv = *(const half8*)(ha + q * 8);
                float4 w0 = *(const float4*)(wor + q * 8);
                float4 w1 = *(const float4*)(wor + q * 8 + 4);
                oa += (float)hv[0]*w0.x + (float)hv[1]*w0.y + (float)hv[2]*w0.z + (float)hv[3]*w0.w
                    + (float)hv[4]*w1.x + (float)hv[5]*w1.y + (float)hv[6]*w1.z + (float)hv[7]*w1.w;
            }
            oa += __shfl_xor(oa, 8, 64);
            oa += __shfl_xor(oa, 16, 64);
            oa += __shfl_xor(oa, 32, 64);
            if (chunk == 0)
                out[((size_t)(gb0 + ob) * Tt + (Tt - 1 - k)) * Ff + f] = oa + bo[f];
        }

        f32x4 acc0 = {0.f, 0.f, 0.f, 0.f}, acc1 = {0.f, 0.f, 0.f, 0.f};
        const _Float16* wrow = &Wlds[(w * 16 + bL) * KPAD + kg * 8];
        const _Float16* arow = &Alds[bL * APAD + kg * 8];
        #pragma unroll
        for (int kt = 0; kt < 16; ++kt) {
            half8 af = *(const half8*)(wrow + kt * 32);
            half8 bf = *(const half8*)(arow + kt * 32);
            if (kt & 1) acc1 = __builtin_amdgcn_mfma_f32_16x16x32_f16(af, bf, acc1, 0, 0, 0);
            else        acc0 = __builtin_amdgcn_mfma_f32_16x16x32_f16(af, bf, acc0, 0, 0, 0);
        }

        float gi = acc0[0] + acc1[0] + bias0;
        float gf = acc0[1] + acc1[1] + bias1;
        float gg = acc0[2] + acc1[2] + bias2;
        float go = acc0[3] + acc1[3] + bias3;
        c = sigf(gf) * c + sigf(gi) * tanhfast(gg);
        float h = sigf(go) * tanhfast(c);
        publish(h, 514 + k);
        __syncthreads();
    }
}

extern "C" void kernel_launch(void* const* d_in, const int* in_sizes, int n_in,
                              void* d_out, int out_size, void* d_ws, size_t ws_size,
                              hipStream_t stream)
{
    (void)in_sizes; (void)n_in; (void)out_size; (void)ws_size;
    const float* ts    = (const float*)d_in[0];
    const float* We_ih = (const float*)d_in[1];
    const float* We_hh = (const float*)d_in[2];
    const float* be    = (const float*)d_in[3];
    const float* Wd_ih = (const float*)d_in[4];
    const float* Wd_hh = (const float*)d_in[5];
    const float* bd    = (const float*)d_in[6];
    const float* Wm    = (const float*)d_in[7];
    const float* bm    = (const float*)d_in[8];
    const float* Wo    = (const float*)d_in[9];
    const float* bo    = (const float*)d_in[10];

    char* ws = (char*)d_ws;
    uint*     hbw  = (uint*)(ws + 0);                         // 524288 B
    _Float16* Weff = (_Float16*)(ws + 524288);                // 2097152 B
    float*    beff = (float*)(ws + 524288 + 2097152);         // 8192 B

    prep_weff<<<4096, 256, 0, stream>>>(Wd_ih, Wd_hh, bd, Wo, bo, Weff, beff);
    lstm_persist<<<256, 256, 0, stream>>>(ts, We_ih, We_hh, be, Wm, bm, Wo, bo,
                                          Weff, beff, hbw, (float*)d_out);
}

// Round 9
// 4167.396 us; speedup vs baseline: 2.9971x; 2.9971x over previous
//
#include <hip/hip_runtime.h>
#include <hip/hip_fp16.h>

#define Tt  512
#define Ff  64
#define Hh  512
#define APAD 520   // Alds row stride (halves)

typedef _Float16 half8 __attribute__((ext_vector_type(8)));
typedef float f32x4 __attribute__((ext_vector_type(4)));
typedef unsigned long long ull;
typedef unsigned short u16;
typedef unsigned int uint;

union HU { _Float16 h; u16 u; };

__device__ __forceinline__ float sigf(float x)     { return 1.0f / (1.0f + __expf(-x)); }
__device__ __forceinline__ float tanhfast(float x) { return 1.0f - 2.0f / (__expf(2.0f * x) + 1.0f); }

// W_eff = Wd_hh + Wd_ih @ Wo  (decoder feedback folded; out becomes pure side-output)
__global__ __launch_bounds__(256) void prep_weff(
    const float* __restrict__ Wd_ih, const float* __restrict__ Wd_hh,
    const float* __restrict__ bd,    const float* __restrict__ Wo,
    const float* __restrict__ bo,    _Float16* __restrict__ W16,
    float* __restrict__ beff)
{
    int idx = blockIdx.x * 256 + threadIdx.x;   // [0, 2048*512)
    int g = idx >> 9, j = idx & 511;
    float acc = Wd_hh[idx];
    const float* wi = Wd_ih + g * Ff;
    #pragma unroll 8
    for (int f = 0; f < Ff; ++f) acc += wi[f] * Wo[f * Hh + j];
    W16[idx] = (_Float16)acc;
    if (j == 0) {
        float b = bd[g];
        for (int f = 0; f < Ff; ++f) b += wi[f] * bo[f];
        beff[g] = b;
    }
}

// Persistent LSTM, 8 groups x 32 members (group = bid&7 — placement-independent).
// Exchange via SYSTEM-scope (sc0 sc1) asm ops — strongest coherence, fresh by
// construction. Flags: ONE per member, fired by the last-arriving wave (LDS
// arrival counter) after its vmcnt(0) drain. Consumer thread tid's 64B slice
// = cols [4*(tid&127), +4) x 16 batches = exactly member (tid>>2)&31's output,
// so each thread polls exactly ONE flag, then stages once. Buffer ping-pong is
// safe without extra sync: publishing s+1 into buf[(s+1)&1] requires all
// members published s, which requires every WG fully STAGED s-1 (loads drained
// before its publish) — the buffer being overwritten is no longer being read.
__global__ __launch_bounds__(256, 1) void lstm_persist(
    const float* __restrict__ ts,
    const float* __restrict__ We_ih, const float* __restrict__ We_hh,
    const float* __restrict__ be,
    const float* __restrict__ Wm,    const float* __restrict__ bm,
    const float* __restrict__ Wo,    const float* __restrict__ bo,
    const _Float16* __restrict__ Weff, const float* __restrict__ beff,
    int* __restrict__ flags,       // [8][32] ints (memset 0 each launch)
    _Float16* __restrict__ hbw,    // [2][8][16][512] fp16 exchange buffers
    float* __restrict__ out)
{
    __shared__ __align__(16) _Float16 Alds[2 * 16 * APAD];  // 33,280 B (dbuf)
    __shared__ short Ballast[25000];                        // 50,000 B -> 1 WG/CU
    __shared__ int cnt_lds;                                 // wave-arrival counter

    const int bid = blockIdx.x;
    const int g = bid & 7, m = bid >> 3;
    const int tid = threadIdx.x;
    const int w = tid >> 6, l = tid & 63;
    const int bL = l & 15, kg = l >> 4;
    const int jj = m * 16 + w * 4 + kg;    // this lane's owned h-column
    const int gb0 = g * 16;

    int* gflags = flags + g * 32;
    _Float16* hb0 = hbw + (size_t)g * 8192;
    _Float16* hb1 = hbw + (size_t)(8 + g) * 8192;

    if (tid == 0) cnt_lds = 0;
    ((volatile short*)Ballast)[tid] = 0;   // keep residency ballast allocated

    int dead = 0;
    int needed = 4;                        // arrival target: 4 waves per publish

    // wait until MY producer published state s (its flag >= s+1)
    auto poll = [&](int s) {
        if (dead) return;
        const int* fp = gflags + ((tid >> 2) & 31);
        const int tgt = s + 1;
        int it = 0, v;
        for (;;) {
            asm volatile("global_load_dword %0, %1, off sc0 sc1\n\t"
                         "s_waitcnt vmcnt(0)"
                         : "=v"(v) : "v"(fp) : "memory");
            if (v >= tgt) break;
            if (++it > 65536) { dead = 1; break; }   // fail fast, no hang
        }
    };

    ull sr[8];
    // load state s tile (16KB) -> Alds[s&1]; system-scope loads, one waitcnt
    auto stage = [&](int s) {
        const ull* src = (const ull*)((s & 1) ? hb1 : hb0) + tid;
        asm volatile("global_load_dwordx2 %0, %1, off sc0 sc1" : "=v"(sr[0]) : "v"(src));
        asm volatile("global_load_dwordx2 %0, %1, off sc0 sc1" : "=v"(sr[1]) : "v"(src + 256));
        asm volatile("global_load_dwordx2 %0, %1, off sc0 sc1" : "=v"(sr[2]) : "v"(src + 512));
        asm volatile("global_load_dwordx2 %0, %1, off sc0 sc1" : "=v"(sr[3]) : "v"(src + 768));
        asm volatile("global_load_dwordx2 %0, %1, off sc0 sc1" : "=v"(sr[4]) : "v"(src + 1024));
        asm volatile("global_load_dwordx2 %0, %1, off sc0 sc1" : "=v"(sr[5]) : "v"(src + 1280));
        asm volatile("global_load_dwordx2 %0, %1, off sc0 sc1" : "=v"(sr[6]) : "v"(src + 1536));
        asm volatile("global_load_dwordx2 %0, %1, off sc0 sc1" : "=v"(sr[7]) : "v"(src + 1792));
        asm volatile("s_waitcnt vmcnt(0)" ::: "memory");
        __builtin_amdgcn_sched_barrier(0);             // rule #18
        _Float16* ab = Alds + (s & 1) * (16 * APAD);
        #pragma unroll
        for (int i = 0; i < 8; ++i) {
            int idx = i * 256 + tid;
            int b_ = idx >> 7, q = idx & 127;          // 128 ull per 512-half row
            *(ull*)&ab[b_ * APAD + q * 4] = sr[i];
        }
    };

    // publish state s; last-arriving wave (LDS counter) fires the member flag
    auto publish = [&](float hval, int s) {
        _Float16* nb = ((s & 1) ? hb1 : hb0) + (bL * 512 + m * 16 + w * 4);
        HU cv; cv.h = (_Float16)hval;
        int hv = (int)cv.u;
        int a0 = __shfl(hv, bL +  0, 64);
        int a1 = __shfl(hv, bL + 16, 64);
        int a2 = __shfl(hv, bL + 32, 64);
        int a3 = __shfl(hv, bL + 48, 64);
        if (l < 16) {
            ull pk = (ull)(uint)((a0 & 0xffff) | (a1 << 16)) |
                     ((ull)(uint)((a2 & 0xffff) | (a3 << 16)) << 32);
            asm volatile("global_store_dwordx2 %0, %1, off sc0 sc1"
                         :: "v"((ull*)nb), "v"(pk) : "memory");
        }
        asm volatile("s_waitcnt vmcnt(0)" ::: "memory");   // this wave's data visible
        __builtin_amdgcn_sched_barrier(0);
        if (l == 0) {
            int old = atomicAdd(&cnt_lds, 1);          // arrival after drain
            if (old == needed - 1) {                   // last wave: all 4 drained
                int* fp = gflags + m;
                int fv = s + 1;
                asm volatile("global_store_dword %0, %1, off sc0 sc1"
                             :: "v"(fp), "v"(fv) : "memory");
            }
        }
        needed += 4;
    };

    // ---- weights -> VGPRs: lane's A-frag row R = w*16+bL, k-slice kg*8 ----
    const int R = w * 16 + bL;
    const int grow = (R & 3) * Hh + m * 16 + (R >> 2);
    half8 af[18];
    {
        const float* wr = We_hh + (size_t)grow * Hh + kg * 8;
        #pragma unroll
        for (int kt = 0; kt < 16; ++kt) {
            float4 a = *(const float4*)(wr + kt * 32);
            float4 b = *(const float4*)(wr + kt * 32 + 4);
            af[kt][0]=(_Float16)a.x; af[kt][1]=(_Float16)a.y; af[kt][2]=(_Float16)a.z; af[kt][3]=(_Float16)a.w;
            af[kt][4]=(_Float16)b.x; af[kt][5]=(_Float16)b.y; af[kt][6]=(_Float16)b.z; af[kt][7]=(_Float16)b.w;
        }
        const float* wx = We_ih + (size_t)grow * Ff + kg * 8;
        #pragma unroll
        for (int kt = 0; kt < 2; ++kt) {
            float4 a = *(const float4*)(wx + kt * 32);
            float4 b = *(const float4*)(wx + kt * 32 + 4);
            af[16+kt][0]=(_Float16)a.x; af[16+kt][1]=(_Float16)a.y; af[16+kt][2]=(_Float16)a.z; af[16+kt][3]=(_Float16)a.w;
            af[16+kt][4]=(_Float16)b.x; af[16+kt][5]=(_Float16)b.y; af[16+kt][6]=(_Float16)b.z; af[16+kt][7]=(_Float16)b.w;
        }
    }
    float bias0 = be[0 * Hh + jj], bias1 = be[1 * Hh + jj],
          bias2 = be[2 * Hh + jj], bias3 = be[3 * Hh + jj];
    float c = 0.f;
    __syncthreads();                       // cnt_lds init visible
    publish(0.f, 0);                       // state 0 = zeros -> flag 1

    // =========================== encoder: 512 steps ===========================
    for (int t = 0; t < Tt; ++t) {
        const float* xp = ts + ((size_t)(gb0 + bL) * Tt + t) * Ff + kg * 8;
        float4 xa0 = *(const float4*)(xp);
        float4 xa1 = *(const float4*)(xp + 4);
        float4 xb0 = *(const float4*)(xp + 32);
        float4 xb1 = *(const float4*)(xp + 36);

        poll(t);
        stage(t);
        __syncthreads();                   // the ONLY per-step barrier

        const _Float16* arow = Alds + (t & 1) * (16 * APAD) + bL * APAD + kg * 8;
        f32x4 acc0 = {0.f,0.f,0.f,0.f}, acc1 = {0.f,0.f,0.f,0.f};
        #pragma unroll
        for (int kt = 0; kt < 16; ++kt) {
            half8 bf = *(const half8*)(arow + kt * 32);
            if (kt & 1) acc1 = __builtin_amdgcn_mfma_f32_16x16x32_f16(af[kt], bf, acc1, 0, 0, 0);
            else        acc0 = __builtin_amdgcn_mfma_f32_16x16x32_f16(af[kt], bf, acc0, 0, 0, 0);
        }
        {   // x tail: kt=16 (x cols 0..31), kt=17 (x cols 32..63)
            half8 bf;
            bf[0]=(_Float16)xa0.x; bf[1]=(_Float16)xa0.y; bf[2]=(_Float16)xa0.z; bf[3]=(_Float16)xa0.w;
            bf[4]=(_Float16)xa1.x; bf[5]=(_Float16)xa1.y; bf[6]=(_Float16)xa1.z; bf[7]=(_Float16)xa1.w;
            acc0 = __builtin_amdgcn_mfma_f32_16x16x32_f16(af[16], bf, acc0, 0, 0, 0);
            half8 bg;
            bg[0]=(_Float16)xb0.x; bg[1]=(_Float16)xb0.y; bg[2]=(_Float16)xb0.z; bg[3]=(_Float16)xb0.w;
            bg[4]=(_Float16)xb1.x; bg[5]=(_Float16)xb1.y; bg[6]=(_Float16)xb1.z; bg[7]=(_Float16)xb1.w;
            acc1 = __builtin_amdgcn_mfma_f32_16x16x32_f16(af[17], bg, acc1, 0, 0, 0);
        }

        float gi = acc0[0] + acc1[0] + bias0;
        float gf = acc0[1] + acc1[1] + bias1;
        float gg = acc0[2] + acc1[2] + bias2;
        float go = acc0[3] + acc1[3] + bias3;
        c = sigf(gf) * c + sigf(gi) * tanhfast(gg);
        float h = sigf(go) * tanhfast(c);
        publish(h, t + 1);
    }

    // ====================== latent + decoder weight reload ======================
    {
        poll(512);
        stage(512);                        // -> Alds parity 0
        __syncthreads();
        int b_ = tid & 15, jc2 = tid >> 4;           // == (bL, w*4+kg)
        int j2 = m * 16 + jc2;
        const float* wmr = Wm + (size_t)j2 * Hh;
        const _Float16* hr = Alds + b_ * APAD;
        float acc = bm[j2];
        #pragma unroll 8
        for (int q = 0; q < 64; ++q) {
            half8 hv = *(const half8*)(hr + q * 8);
            float4 w0 = *(const float4*)(wmr + q * 8);
            float4 w1 = *(const float4*)(wmr + q * 8 + 4);
            acc += (float)hv[0]*w0.x + (float)hv[1]*w0.y + (float)hv[2]*w0.z + (float)hv[3]*w0.w
                 + (float)hv[4]*w1.x + (float)hv[5]*w1.y + (float)hv[6]*w1.z + (float)hv[7]*w1.w;
        }
        // decoder weights -> VGPRs (Weff already fp16); drained by publish's vmcnt
        const _Float16* dr = Weff + (size_t)grow * Hh + kg * 8;
        #pragma unroll
        for (int kt = 0; kt < 16; ++kt) af[kt] = *(const half8*)(dr + kt * 32);
        bias0 = beff[0 * Hh + jj]; bias1 = beff[1 * Hh + jj];
        bias2 = beff[2 * Hh + jj]; bias3 = beff[3 * Hh + jj];
        publish(acc, 513);                 // h_lat becomes decoder h-state
        __syncthreads();
    }

    // =========================== decoder: 512 steps ===========================
    for (int k = 0; k < Tt; ++k) {
        const int s = 513 + k;
        poll(s);
        stage(s);
        __syncthreads();

        const _Float16* ab = Alds + (s & 1) * (16 * APAD);
        const _Float16* arow = ab + bL * APAD + kg * 8;
        f32x4 acc0 = {0.f,0.f,0.f,0.f}, acc1 = {0.f,0.f,0.f,0.f};
        #pragma unroll
        for (int kt = 0; kt < 16; ++kt) {
            half8 bf = *(const half8*)(arow + kt * 32);
            if (kt & 1) acc1 = __builtin_amdgcn_mfma_f32_16x16x32_f16(af[kt], bf, acc1, 0, 0, 0);
            else        acc0 = __builtin_amdgcn_mfma_f32_16x16x32_f16(af[kt], bf, acc0, 0, 0, 0);
        }

        float gi = acc0[0] + acc1[0] + bias0;
        float gf = acc0[1] + acc1[1] + bias1;
        float gg = acc0[2] + acc1[2] + bias2;
        float go = acc0[3] + acc1[3] + bias3;
        c = sigf(gf) * c + sigf(gi) * tanhfast(gg);
        float h = sigf(go) * tanhfast(c);
        publish(h, s + 1);                 // fire flag FIRST (recurrence path)

        // out[:, 511-k, :] = h @ Wo.T + bo — off the critical path, after publish.
        // FULL K coverage: cols = chunk*8 + q*64 + e, q<8 -> [0,512). 32 (b,f)
        // pairs: pr = w*8+(l&7): ob=pr&15, fs=pr>>4; reduce over chunk=l>>3.
        {
            int c8 = l & 7, chunk = l >> 3;
            int pr = w * 8 + c8;
            int ob = pr & 15, fs = pr >> 4;
            int f = 2 * m + fs;
            const float* wor = Wo + (size_t)f * Hh + chunk * 8;
            const _Float16* ha = ab + ob * APAD + chunk * 8;
            float oa = 0.f;
            #pragma unroll
            for (int q = 0; q < 8; ++q) {
                half8 hv = *(const half8*)(ha + q * 64);
                float4 w0 = *(const float4*)(wor + q * 64);
                float4 w1 = *(const float4*)(wor + q * 64 + 4);
                oa += (float)hv[0]*w0.x + (float)hv[1]*w0.y + (float)hv[2]*w0.z + (float)hv[3]*w0.w
                    + (float)hv[4]*w1.x + (float)hv[5]*w1.y + (float)hv[6]*w1.z + (float)hv[7]*w1.w;
            }
            oa += __shfl_xor(oa, 8, 64);
            oa += __shfl_xor(oa, 16, 64);
            oa += __shfl_xor(oa, 32, 64);
            if (chunk == 0)
                out[((size_t)(gb0 + ob) * Tt + (Tt - 1 - k)) * Ff + f] = oa + bo[f];
        }
    }
}

extern "C" void kernel_launch(void* const* d_in, const int* in_sizes, int n_in,
                              void* d_out, int out_size, void* d_ws, size_t ws_size,
                              hipStream_t stream)
{
    (void)in_sizes; (void)n_in; (void)out_size; (void)ws_size;
    const float* ts    = (const float*)d_in[0];
    const float* We_ih = (const float*)d_in[1];
    const float* We_hh = (const float*)d_in[2];
    const float* be    = (const float*)d_in[3];
    const float* Wd_ih = (const float*)d_in[4];
    const float* Wd_hh = (const float*)d_in[5];
    const float* bd    = (const float*)d_in[6];
    const float* Wm    = (const float*)d_in[7];
    const float* bm    = (const float*)d_in[8];
    const float* Wo    = (const float*)d_in[9];
    const float* bo    = (const float*)d_in[10];

    char* ws = (char*)d_ws;
    int*      flags = (int*)ws;                               // 1024 B used
    _Float16* hbw   = (_Float16*)(ws + 8192);                 // 262144 B
    _Float16* Weff  = (_Float16*)(ws + 8192 + 262144);        // 2097152 B
    float*    beff  = (float*)(ws + 8192 + 262144 + 2097152); // 8192 B

    hipMemsetAsync(ws, 0, 8192, stream);   // flags
    prep_weff<<<4096, 256, 0, stream>>>(Wd_ih, Wd_hh, bd, Wo, bo, Weff, beff);
    lstm_persist<<<256, 256, 0, stream>>>(ts, We_ih, We_hh, be, Wm, bm, Wo, bo,
                                          Weff, beff, flags, hbw, (float*)d_out);
}